// Round 5
// baseline (174.722 us; speedup 1.0000x reference)
//
#include <hip/hip_runtime.h>
#include <hip/hip_bf16.h>

typedef float f32x4 __attribute__((ext_vector_type(4)));
typedef long lx2 __attribute__((ext_vector_type(2)));

#define FP8_MAX_F 448.0f

__device__ __forceinline__ float wave_max(float m) {
#pragma unroll
    for (int off = 32; off > 0; off >>= 1)
        m = fmaxf(m, __shfl_xor(m, off));
    return m;
}

// ---------------- stage 1: per-block abs-max partials (no atomics) ----------------
__global__ void amax2_kernel(const float* __restrict__ x, long nx,
                             const float* __restrict__ w, long nw,
                             float* __restrict__ px, float* __restrict__ pw,
                             int ga) {
    __shared__ float red[4];
    const float* src; long n; float* dst; int bid, blocks;
    if ((int)blockIdx.x < ga) { src = x; n = nx; dst = px; bid = blockIdx.x; blocks = ga; }
    else { src = w; n = nw; dst = pw; bid = blockIdx.x - ga; blocks = gridDim.x - ga; }

    const long stride = (long)blocks * blockDim.x * 16;
    long i = ((long)bid * blockDim.x + threadIdx.x) * 16;
    float m = 0.0f;
    for (; i < n; i += stride) {
        f32x4 v0 = *(const f32x4*)(src + i);
        f32x4 v1 = *(const f32x4*)(src + i + 4);
        f32x4 v2 = *(const f32x4*)(src + i + 8);
        f32x4 v3 = *(const f32x4*)(src + i + 12);
        float m0 = fmaxf(fmaxf(fabsf(v0.x), fabsf(v0.y)), fmaxf(fabsf(v0.z), fabsf(v0.w)));
        float m1 = fmaxf(fmaxf(fabsf(v1.x), fabsf(v1.y)), fmaxf(fabsf(v1.z), fabsf(v1.w)));
        float m2 = fmaxf(fmaxf(fabsf(v2.x), fabsf(v2.y)), fmaxf(fabsf(v2.z), fabsf(v2.w)));
        float m3 = fmaxf(fmaxf(fabsf(v3.x), fabsf(v3.y)), fmaxf(fabsf(v3.z), fabsf(v3.w)));
        m = fmaxf(m, fmaxf(fmaxf(m0, m1), fmaxf(m2, m3)));
    }
    m = wave_max(m);
    const int wave = threadIdx.x >> 6;
    if ((threadIdx.x & 63) == 0) red[wave] = m;
    __syncthreads();
    if (threadIdx.x == 0)
        dst[bid] = fmaxf(fmaxf(red[0], red[1]), fmaxf(red[2], red[3]));
}

// ---------------- stage 2: reduce partials -> amax bits (block 0 = x, block 1 = w) ----------------
__global__ void amax_final_kernel(const float* __restrict__ px, int npx,
                                  const float* __restrict__ pw, int npw,
                                  unsigned* __restrict__ amax) {
    __shared__ float red[4];
    const float* p; int n;
    if (blockIdx.x == 0) { p = px; n = npx; } else { p = pw; n = npw; }
    float m = 0.0f;
    for (int i = threadIdx.x; i < n; i += blockDim.x) m = fmaxf(m, p[i]);
    m = wave_max(m);
    const int wave = threadIdx.x >> 6;
    if ((threadIdx.x & 63) == 0) red[wave] = m;
    __syncthreads();
    if (threadIdx.x == 0) {
        m = fmaxf(fmaxf(red[0], red[1]), fmaxf(red[2], red[3]));
        amax[blockIdx.x] = __float_as_uint(m);
    }
}

// ---------------- fused quantize (8 floats/thread/iter -> uint2) ----------------
__global__ void quant2_kernel(const float* __restrict__ x, long nx8,
                              const float* __restrict__ w, long nw8,
                              const unsigned* __restrict__ amax_bits,
                              unsigned* __restrict__ qx, unsigned* __restrict__ qw,
                              int ga) {
    const float* src; long n8; unsigned* q; int bid, blocks; float a;
    if ((int)blockIdx.x < ga) { src = x; n8 = nx8; q = qx; bid = blockIdx.x; blocks = ga;
                                a = __uint_as_float(amax_bits[0]); }
    else { src = w; n8 = nw8; q = qw; bid = blockIdx.x - ga; blocks = gridDim.x - ga;
           a = __uint_as_float(amax_bits[1]); }
    const float scale = fminf(FP8_MAX_F / fmaxf(a, 1e-12f), FP8_MAX_F);

    const long stride = (long)blocks * blockDim.x;
    for (long i = (long)bid * blockDim.x + threadIdx.x; i < n8; i += stride) {
        f32x4 v0 = *(const f32x4*)(src + i * 8);
        f32x4 v1 = *(const f32x4*)(src + i * 8 + 4);
        float c0 = fminf(fmaxf(v0.x * scale, -FP8_MAX_F), FP8_MAX_F);
        float c1 = fminf(fmaxf(v0.y * scale, -FP8_MAX_F), FP8_MAX_F);
        float c2 = fminf(fmaxf(v0.z * scale, -FP8_MAX_F), FP8_MAX_F);
        float c3 = fminf(fmaxf(v0.w * scale, -FP8_MAX_F), FP8_MAX_F);
        float c4 = fminf(fmaxf(v1.x * scale, -FP8_MAX_F), FP8_MAX_F);
        float c5 = fminf(fmaxf(v1.y * scale, -FP8_MAX_F), FP8_MAX_F);
        float c6 = fminf(fmaxf(v1.z * scale, -FP8_MAX_F), FP8_MAX_F);
        float c7 = fminf(fmaxf(v1.w * scale, -FP8_MAX_F), FP8_MAX_F);
        int r0 = __builtin_amdgcn_cvt_pk_fp8_f32(c0, c1, 0, false);
        r0 = __builtin_amdgcn_cvt_pk_fp8_f32(c2, c3, r0, true);
        int r1 = __builtin_amdgcn_cvt_pk_fp8_f32(c4, c5, 0, false);
        r1 = __builtin_amdgcn_cvt_pk_fp8_f32(c6, c7, r1, true);
        uint2 rr; rr.x = (unsigned)r0; rr.y = (unsigned)r1;
        *(uint2*)(q + i * 2) = rr;
    }
}

// ---------------- fp8 GEMM, 256x128 tile, BK=64, 1-barrier/tile pipelined ----------------
// LDS per slot: A linear [c=0..3][row=0..255][16B], B linear [c=0..3][row=0..127][16B].
// Lane (l15,lhi) ds_read_b128's its (row, c=lhi) unit; bytes 0..7 = MFMA k-step 0,
// bytes 8..15 = k-step 1 (same k->slot map on A and B). Conflict-free by construction.
// Per tile: vmcnt(0) [own stage only] -> barrier -> 8 ds_read -> STAGE next -> lgkm(0) -> 32 MFMA.
// WAR-safe with a single barrier: every wave drains its reads (lgkm0) before the next barrier.
__global__ __launch_bounds__(512, 4) void gemm_fp8_kernel(
    const unsigned char* __restrict__ Xq,   // [M][K] fp8
    const unsigned char* __restrict__ Wq,   // [N][K] fp8
    const float* __restrict__ bias,         // [N]
    const unsigned* __restrict__ amax_bits, // [0]=x amax, [1]=w amax
    float* __restrict__ out,                // [M][N] f32 (bf16-rounded values)
    int M, int N, int K, int nbn)
{
    __shared__ unsigned char ldsA[2][16384];
    __shared__ unsigned char ldsB[2][8192];

    const int tid  = threadIdx.x;
    const int lane = tid & 63;
    const int wave = tid >> 6;
    const int wm64 = (wave >> 1) * 64;    // 4 M-quarters of 256
    const int wn64 = (wave & 1) * 64;     // 2 N-halves of 128

    const int l15 = lane & 15;
    const int lhi = lane >> 4;            // 0..3 -> which 16B k-chunk

    // XCD-aware swizzle (nwg % 8 == 0), bn-fastest: 16 A-panels (4MB) + B per XCD chunk
    const int cpx = gridDim.x >> 3;
    const int wg  = ((int)blockIdx.x & 7) * cpx + ((int)blockIdx.x >> 3);
    const int bn = wg % nbn;
    const int bm = wg / nbn;
    const int rowStart = bm << 8;
    const int colStart = bn << 7;

    // LDS read offsets (linear layout)
    const int aoff = lhi * 4096 + (wm64 + l15) * 16;
    const int boff = lhi * 2048 + (wn64 + l15) * 16;

    // staging source offsets (fully linear)
    const size_t aoffs = (size_t)(rowStart + (tid & 255)) * K + (tid >> 8) * 16;
    const size_t boffs = (size_t)(colStart + (tid & 127)) * K + (tid >> 7) * 16;
    const int tid16 = tid * 16;

    f32x4 acc[4][4] = {};

#define STAGE(t, slot)                                                                          \
    do {                                                                                        \
        const size_t kk_ = (size_t)(t) * 64;                                                    \
        __builtin_amdgcn_global_load_lds(                                                       \
            (const __attribute__((address_space(1))) void*)(Xq + aoffs + kk_),                  \
            (__attribute__((address_space(3))) void*)(&ldsA[slot][tid16]), 16, 0, 0);           \
        __builtin_amdgcn_global_load_lds(                                                       \
            (const __attribute__((address_space(1))) void*)(Xq + aoffs + 32 + kk_),             \
            (__attribute__((address_space(3))) void*)(&ldsA[slot][8192 + tid16]), 16, 0, 0);    \
        __builtin_amdgcn_global_load_lds(                                                       \
            (const __attribute__((address_space(1))) void*)(Wq + boffs + kk_),                  \
            (__attribute__((address_space(3))) void*)(&ldsB[slot][tid16]), 16, 0, 0);           \
    } while (0)

#define TILE(slot, STG)                                                                         \
    do {                                                                                        \
        asm volatile("s_waitcnt vmcnt(0)" ::: "memory");                                        \
        __builtin_amdgcn_s_barrier();                                                           \
        __builtin_amdgcn_sched_barrier(0);                                                      \
        lx2 af[4], bf[4];                                                                       \
        _Pragma("unroll")                                                                       \
        for (int q_ = 0; q_ < 4; ++q_) {                                                        \
            af[q_] = *(const lx2*)(&ldsA[slot][aoff + q_ * 256]);                               \
            bf[q_] = *(const lx2*)(&ldsB[slot][boff + q_ * 256]);                               \
        }                                                                                       \
        STG;                                                                                    \
        asm volatile("s_waitcnt lgkmcnt(0)" ::: "memory");                                      \
        __builtin_amdgcn_sched_barrier(0);                                                      \
        __builtin_amdgcn_s_setprio(1);                                                          \
        _Pragma("unroll")                                                                       \
        for (int ks_ = 0; ks_ < 2; ++ks_)                                                       \
            _Pragma("unroll")                                                                   \
            for (int mi_ = 0; mi_ < 4; ++mi_)                                                   \
                _Pragma("unroll")                                                               \
                for (int ni_ = 0; ni_ < 4; ++ni_)                                               \
                    acc[mi_][ni_] = __builtin_amdgcn_mfma_f32_16x16x32_fp8_fp8(                 \
                        af[mi_][ks_], bf[ni_][ks_], acc[mi_][ni_], 0, 0, 0);                    \
        __builtin_amdgcn_s_setprio(0);                                                          \
    } while (0)

    // prologue: tile 0 -> slot 0
    STAGE(0, 0);

    const int nIter = K >> 7;   // pairs of BK=64 tiles (= 8 for K=1024)
#pragma unroll 1
    for (int i = 0; i < nIter; ++i) {
        TILE(0, STAGE(2 * i + 1, 1));
        TILE(1, do { if (i < nIter - 1) STAGE(2 * i + 2, 0); } while (0));
    }
#undef TILE
#undef STAGE

    // ---- epilogue: dequant scale, bias, bf16 round, f32 store ----
    const float ax = __uint_as_float(amax_bits[0]);
    const float aw = __uint_as_float(amax_bits[1]);
    const float sx = fminf(FP8_MAX_F / fmaxf(ax, 1e-12f), FP8_MAX_F);
    const float sw = fminf(FP8_MAX_F / fmaxf(aw, 1e-12f), FP8_MAX_F);
    const float s  = (1.0f / sx) * (1.0f / sw);

    const int lhi4 = lhi * 4;
#pragma unroll
    for (int ni = 0; ni < 4; ++ni) {
        const int col = colStart + wn64 + ni * 16 + l15;
        const float bv = bias[col];
#pragma unroll
        for (int mi = 0; mi < 4; ++mi) {
            const size_t rbase = (size_t)(rowStart + wm64 + mi * 16 + lhi4) * N + col;
#pragma unroll
            for (int j = 0; j < 4; ++j) {
                float t = acc[mi][ni][j] * s;   // mul...
                t = t + bv;                     // ...then add (match jnp op order)
                out[rbase + (size_t)j * N] = __bfloat162float(__float2bfloat16(t));
            }
        }
    }
}

extern "C" void kernel_launch(void* const* d_in, const int* in_sizes, int n_in,
                              void* d_out, int out_size, void* d_ws, size_t ws_size,
                              hipStream_t stream) {
    const float* input  = (const float*)d_in[0];
    const float* weight = (const float*)d_in[1];
    const float* bias   = (const float*)d_in[2];
    float* out = (float*)d_out;

    const int K = 1024;                       // weight [N,K] = [1024,1024]
    const int N = in_sizes[2];                // 1024 (bias length)
    const long nX = in_sizes[0];              // 33554432
    const long nW = (long)N * K;              // 1048576
    const int M = (int)(nX / K);              // 32768

    const int GA = 1984;                      // input blocks (of 2048 total)
    const int GW = 64;                        // weight blocks

    unsigned char* ws = (unsigned char*)d_ws;
    unsigned* amax = (unsigned*)ws;           // [0]=x amax bits, [1]=w amax bits
    unsigned char* Xq = ws + 256;
    unsigned char* Wq = Xq + (size_t)M * K;
    float* px = (float*)(Wq + (size_t)N * K); // 1984 partials
    float* pw = px + GA;                      // 64 partials

    // stage 1: per-block partials (plain stores, no atomic contention)
    amax2_kernel<<<GA + GW, 256, 0, stream>>>(input, nX, weight, nW, px, pw, GA);
    // stage 2: 2 blocks reduce partials -> amax bits (deterministic)
    amax_final_kernel<<<2, 256, 0, stream>>>(px, GA, pw, GW, amax);

    quant2_kernel<<<2048, 256, 0, stream>>>(input, nX / 8, weight, nW / 8, amax,
                                            (unsigned*)Xq, (unsigned*)Wq, GA);

    const int nbn = N / 128;                  // 8
    const int nwg = (M / 256) * nbn;          // 1024 -> 2 generations at 2 blocks/CU
    gemm_fp8_kernel<<<dim3(nwg), dim3(512), 0, stream>>>(Xq, Wq, bias, amax, out, M, N, K, nbn);
}

// Round 6
// 134.400 us; speedup vs baseline: 1.3000x; 1.3000x over previous
//
#include <hip/hip_runtime.h>
#include <hip/hip_bf16.h>

typedef float f32x4 __attribute__((ext_vector_type(4)));
typedef long lx2 __attribute__((ext_vector_type(2)));

#define FP8_MAX_F 448.0f

__device__ __forceinline__ float wave_max(float m) {
#pragma unroll
    for (int off = 32; off > 0; off >>= 1)
        m = fmaxf(m, __shfl_xor(m, off));
    return m;
}

// ---------------- stage 1: per-block abs-max partials (no atomics) ----------------
__global__ void amax2_kernel(const float* __restrict__ x, long nx,
                             const float* __restrict__ w, long nw,
                             float* __restrict__ px, float* __restrict__ pw,
                             int ga) {
    __shared__ float red[4];
    const float* src; long n; float* dst; int bid, blocks;
    if ((int)blockIdx.x < ga) { src = x; n = nx; dst = px; bid = blockIdx.x; blocks = ga; }
    else { src = w; n = nw; dst = pw; bid = blockIdx.x - ga; blocks = gridDim.x - ga; }

    const long stride = (long)blocks * blockDim.x * 16;
    long i = ((long)bid * blockDim.x + threadIdx.x) * 16;
    float m = 0.0f;
    for (; i < n; i += stride) {
        f32x4 v0 = *(const f32x4*)(src + i);
        f32x4 v1 = *(const f32x4*)(src + i + 4);
        f32x4 v2 = *(const f32x4*)(src + i + 8);
        f32x4 v3 = *(const f32x4*)(src + i + 12);
        float m0 = fmaxf(fmaxf(fabsf(v0.x), fabsf(v0.y)), fmaxf(fabsf(v0.z), fabsf(v0.w)));
        float m1 = fmaxf(fmaxf(fabsf(v1.x), fabsf(v1.y)), fmaxf(fabsf(v1.z), fabsf(v1.w)));
        float m2 = fmaxf(fmaxf(fabsf(v2.x), fabsf(v2.y)), fmaxf(fabsf(v2.z), fabsf(v2.w)));
        float m3 = fmaxf(fmaxf(fabsf(v3.x), fabsf(v3.y)), fmaxf(fabsf(v3.z), fabsf(v3.w)));
        m = fmaxf(m, fmaxf(fmaxf(m0, m1), fmaxf(m2, m3)));
    }
    m = wave_max(m);
    const int wave = threadIdx.x >> 6;
    if ((threadIdx.x & 63) == 0) red[wave] = m;
    __syncthreads();
    if (threadIdx.x == 0)
        dst[bid] = fmaxf(fmaxf(red[0], red[1]), fmaxf(red[2], red[3]));
}

// ---------------- stage 2: reduce partials -> amax bits (block 0 = x, block 1 = w) ----------------
__global__ void amax_final_kernel(const float* __restrict__ px, int npx,
                                  const float* __restrict__ pw, int npw,
                                  unsigned* __restrict__ amax) {
    __shared__ float red[4];
    const float* p; int n;
    if (blockIdx.x == 0) { p = px; n = npx; } else { p = pw; n = npw; }
    float m = 0.0f;
    for (int i = threadIdx.x; i < n; i += blockDim.x) m = fmaxf(m, p[i]);
    m = wave_max(m);
    const int wave = threadIdx.x >> 6;
    if ((threadIdx.x & 63) == 0) red[wave] = m;
    __syncthreads();
    if (threadIdx.x == 0) {
        m = fmaxf(fmaxf(red[0], red[1]), fmaxf(red[2], red[3]));
        amax[blockIdx.x] = __float_as_uint(m);
    }
}

// ---------------- fused quantize (8 floats/thread/iter -> uint2) ----------------
__global__ void quant2_kernel(const float* __restrict__ x, long nx8,
                              const float* __restrict__ w, long nw8,
                              const unsigned* __restrict__ amax_bits,
                              unsigned* __restrict__ qx, unsigned* __restrict__ qw,
                              int ga) {
    const float* src; long n8; unsigned* q; int bid, blocks; float a;
    if ((int)blockIdx.x < ga) { src = x; n8 = nx8; q = qx; bid = blockIdx.x; blocks = ga;
                                a = __uint_as_float(amax_bits[0]); }
    else { src = w; n8 = nw8; q = qw; bid = blockIdx.x - ga; blocks = gridDim.x - ga;
           a = __uint_as_float(amax_bits[1]); }
    const float scale = fminf(FP8_MAX_F / fmaxf(a, 1e-12f), FP8_MAX_F);

    const long stride = (long)blocks * blockDim.x;
    for (long i = (long)bid * blockDim.x + threadIdx.x; i < n8; i += stride) {
        f32x4 v0 = *(const f32x4*)(src + i * 8);
        f32x4 v1 = *(const f32x4*)(src + i * 8 + 4);
        float c0 = fminf(fmaxf(v0.x * scale, -FP8_MAX_F), FP8_MAX_F);
        float c1 = fminf(fmaxf(v0.y * scale, -FP8_MAX_F), FP8_MAX_F);
        float c2 = fminf(fmaxf(v0.z * scale, -FP8_MAX_F), FP8_MAX_F);
        float c3 = fminf(fmaxf(v0.w * scale, -FP8_MAX_F), FP8_MAX_F);
        float c4 = fminf(fmaxf(v1.x * scale, -FP8_MAX_F), FP8_MAX_F);
        float c5 = fminf(fmaxf(v1.y * scale, -FP8_MAX_F), FP8_MAX_F);
        float c6 = fminf(fmaxf(v1.z * scale, -FP8_MAX_F), FP8_MAX_F);
        float c7 = fminf(fmaxf(v1.w * scale, -FP8_MAX_F), FP8_MAX_F);
        int r0 = __builtin_amdgcn_cvt_pk_fp8_f32(c0, c1, 0, false);
        r0 = __builtin_amdgcn_cvt_pk_fp8_f32(c2, c3, r0, true);
        int r1 = __builtin_amdgcn_cvt_pk_fp8_f32(c4, c5, 0, false);
        r1 = __builtin_amdgcn_cvt_pk_fp8_f32(c6, c7, r1, true);
        uint2 rr; rr.x = (unsigned)r0; rr.y = (unsigned)r1;
        *(uint2*)(q + i * 2) = rr;
    }
}

// ---------------- fp8 GEMM, 256x256 tile, BK=64, 3-slot 4-phase pipelined ----------------
// LDS per slot/side: linear [c=0..3][row=0..255][16B]. Lane (l15,lhi) ds_read_b128's unit
// (row, c=lhi); bytes 0..7 = MFMA k-step 0, bytes 8..15 = k-step 1 (same k->slot map on A
// and B) -> conflict-free (R4-verified, SQ_LDS_BANK_CONFLICT=0).
// Pipeline: S(t+2) staged into slot (t+2)%3 during tile t; tile boundary = counted
// vmcnt(4) (S(t+1)'s 4 loads stay in flight) + barrier publish. 4 phases/tile, 16-MFMA
// clusters, setprio role-split. WAR-safe: slot's last reads drained (lgkm0) >=2 barriers
// before its restage; RAW-safe: in-order vmcnt retirement + publish barrier.
__global__ __launch_bounds__(512, 2) void gemm_fp8_kernel(
    const unsigned char* __restrict__ Xq,   // [M][K] fp8
    const unsigned char* __restrict__ Wq,   // [N][K] fp8
    const float* __restrict__ bias,         // [N]
    const unsigned* __restrict__ amax_bits, // [0]=x amax, [1]=w amax
    float* __restrict__ out,                // [M][N] f32 (bf16-rounded values)
    int M, int N, int K, int nbn)
{
    __shared__ unsigned char ldsA[3][16384];
    __shared__ unsigned char ldsB[3][16384];

    const int tid  = threadIdx.x;
    const int lane = tid & 63;
    const int wave = tid >> 6;
    const int wm128 = (wave >> 2) * 128;  // 2 M-halves
    const int wn64  = (wave & 3) * 64;    // 4 N-quarters

    const int l15 = lane & 15;
    const int lhi = lane >> 4;            // 0..3 -> which 16B k-chunk

    // XCD-aware swizzle (nwg % 8 == 0), bn-fastest for A-panel L2 reuse
    const int cpx = gridDim.x >> 3;
    const int wg  = ((int)blockIdx.x & 7) * cpx + ((int)blockIdx.x >> 3);
    const int bn = wg % nbn;
    const int bm = wg / nbn;
    const int rowStart = bm << 8;
    const int colStart = bn << 8;

    // LDS read offsets (linear layout)
    const int aoff0 = lhi * 4096 + (wm128 + l15) * 16;   // mh=0; mh=1 at +1024
    const int boff  = lhi * 4096 + (wn64 + l15) * 16;

    // staging source offsets (fully linear)
    const size_t aoffs = (size_t)(rowStart + (tid & 255)) * K + (tid >> 8) * 16;
    const size_t boffs = (size_t)(colStart + (tid & 255)) * K + (tid >> 8) * 16;
    const int tid16 = tid * 16;

    f32x4 acc[8][4] = {};

#define STAGE_A(t, sl)                                                                          \
    do {                                                                                        \
        const size_t kk_ = (size_t)(t) * 64;                                                    \
        __builtin_amdgcn_global_load_lds(                                                       \
            (const __attribute__((address_space(1))) void*)(Xq + aoffs + kk_),                  \
            (__attribute__((address_space(3))) void*)(&ldsA[sl][tid16]), 16, 0, 0);             \
        __builtin_amdgcn_global_load_lds(                                                       \
            (const __attribute__((address_space(1))) void*)(Xq + aoffs + 32 + kk_),             \
            (__attribute__((address_space(3))) void*)(&ldsA[sl][8192 + tid16]), 16, 0, 0);      \
    } while (0)

#define STAGE_B(t, sl)                                                                          \
    do {                                                                                        \
        const size_t kk_ = (size_t)(t) * 64;                                                    \
        __builtin_amdgcn_global_load_lds(                                                       \
            (const __attribute__((address_space(1))) void*)(Wq + boffs + kk_),                  \
            (__attribute__((address_space(3))) void*)(&ldsB[sl][tid16]), 16, 0, 0);             \
        __builtin_amdgcn_global_load_lds(                                                       \
            (const __attribute__((address_space(1))) void*)(Wq + boffs + 32 + kk_),             \
            (__attribute__((address_space(3))) void*)(&ldsB[sl][8192 + tid16]), 16, 0, 0);      \
    } while (0)

#define MFMA16(AF, KS, MO)                                                                      \
    do {                                                                                        \
        __builtin_amdgcn_s_setprio(1);                                                          \
        _Pragma("unroll")                                                                       \
        for (int mi_ = 0; mi_ < 4; ++mi_)                                                       \
            _Pragma("unroll")                                                                   \
            for (int ni_ = 0; ni_ < 4; ++ni_)                                                   \
                acc[(MO) + mi_][ni_] = __builtin_amdgcn_mfma_f32_16x16x32_fp8_fp8(              \
                    AF[mi_][KS], bf[ni_][KS], acc[(MO) + mi_][ni_], 0, 0, 0);                   \
        __builtin_amdgcn_s_setprio(0);                                                          \
    } while (0)

#define BAR()  do { __builtin_amdgcn_s_barrier(); __builtin_amdgcn_sched_barrier(0); } while (0)
#define LGKM0() do { asm volatile("s_waitcnt lgkmcnt(0)" ::: "memory");                         \
                     __builtin_amdgcn_sched_barrier(0); } while (0)

    // prologue: stage tiles 0,1 into slots 0,1; publish tile 0 (counted: S(1) stays in flight)
    STAGE_A(0, 0); STAGE_B(0, 0);
    STAGE_A(1, 1); STAGE_B(1, 1);
    asm volatile("s_waitcnt vmcnt(4)" ::: "memory");
    __builtin_amdgcn_s_barrier();
    __builtin_amdgcn_sched_barrier(0);

    const int nT = K >> 6;   // 16
    int s = 0;
#pragma unroll 1
    for (int t = 0; t < nT; ++t) {
        const unsigned char* bA = &ldsA[s][0];
        const unsigned char* bB = &ldsB[s][0];
        const int s2 = (s >= 1) ? (s - 1) : (s + 2);   // (s+2)%3
        lx2 af[4], bf[4], ag[4];

        // ---- P0: read bf + af(mh0); stage A of t+2 ----
#pragma unroll
        for (int q_ = 0; q_ < 4; ++q_) {
            bf[q_] = *(const lx2*)(bB + boff + q_ * 256);
            af[q_] = *(const lx2*)(bA + aoff0 + q_ * 256);
        }
        if (t + 2 < nT) STAGE_A(t + 2, s2);
        BAR();
        LGKM0();
        MFMA16(af, 0, 0);
        BAR();

        // ---- P1: read af(mh1); stage B of t+2 ----
#pragma unroll
        for (int q_ = 0; q_ < 4; ++q_)
            ag[q_] = *(const lx2*)(bA + aoff0 + 1024 + q_ * 256);
        if (t + 2 < nT) STAGE_B(t + 2, s2);
        BAR();
        MFMA16(af, 1, 0);
        BAR();

        // ---- P2 ----
        LGKM0();
        MFMA16(ag, 0, 4);
        BAR();

        // ---- P3 + tile-boundary publish ----
        MFMA16(ag, 1, 4);
        if (t >= nT - 2) asm volatile("s_waitcnt vmcnt(0)" ::: "memory");
        else             asm volatile("s_waitcnt vmcnt(4)" ::: "memory");
        BAR();

        s = (s == 2) ? 0 : (s + 1);
    }
#undef STAGE_A
#undef STAGE_B
#undef MFMA16
#undef BAR
#undef LGKM0

    // ---- epilogue: dequant scale, bias, bf16 round, f32 store ----
    const float ax = __uint_as_float(amax_bits[0]);
    const float aw = __uint_as_float(amax_bits[1]);
    const float sx = fminf(FP8_MAX_F / fmaxf(ax, 1e-12f), FP8_MAX_F);
    const float sw = fminf(FP8_MAX_F / fmaxf(aw, 1e-12f), FP8_MAX_F);
    const float sc = (1.0f / sx) * (1.0f / sw);

    const int lhi4 = lhi * 4;
#pragma unroll
    for (int ni = 0; ni < 4; ++ni) {
        const int col = colStart + wn64 + ni * 16 + l15;
        const float bv = bias[col];
#pragma unroll
        for (int mi = 0; mi < 8; ++mi) {
            const size_t rbase = (size_t)(rowStart + wm128 + mi * 16 + lhi4) * N + col;
#pragma unroll
            for (int j = 0; j < 4; ++j) {
                float t = acc[mi][ni][j] * sc;  // mul...
                t = t + bv;                     // ...then add (match jnp op order)
                out[rbase + (size_t)j * N] = __bfloat162float(__float2bfloat16(t));
            }
        }
    }
}

extern "C" void kernel_launch(void* const* d_in, const int* in_sizes, int n_in,
                              void* d_out, int out_size, void* d_ws, size_t ws_size,
                              hipStream_t stream) {
    const float* input  = (const float*)d_in[0];
    const float* weight = (const float*)d_in[1];
    const float* bias   = (const float*)d_in[2];
    float* out = (float*)d_out;

    const int K = 1024;                       // weight [N,K] = [1024,1024]
    const int N = in_sizes[2];                // 1024 (bias length)
    const long nX = in_sizes[0];              // 33554432
    const long nW = (long)N * K;              // 1048576
    const int M = (int)(nX / K);              // 32768

    const int GA = 1984;                      // input blocks (of 2048 total)
    const int GW = 64;                        // weight blocks

    unsigned char* ws = (unsigned char*)d_ws;
    unsigned* amax = (unsigned*)ws;           // [0]=x amax bits, [1]=w amax bits
    unsigned char* Xq = ws + 256;
    unsigned char* Wq = Xq + (size_t)M * K;
    float* px = (float*)(Wq + (size_t)N * K); // 1984 partials
    float* pw = px + GA;                      // 64 partials

    // stage 1: per-block partials (plain stores, no atomic contention)
    amax2_kernel<<<GA + GW, 256, 0, stream>>>(input, nX, weight, nW, px, pw, GA);
    // stage 2: 2 blocks reduce partials -> amax bits (deterministic)
    amax_final_kernel<<<2, 256, 0, stream>>>(px, GA, pw, GW, amax);

    quant2_kernel<<<2048, 256, 0, stream>>>(input, nX / 8, weight, nW / 8, amax,
                                            (unsigned*)Xq, (unsigned*)Wq, GA);

    const int nbn = N / 256;                  // 4
    const int nwg = (M / 256) * nbn;          // 512
    gemm_fp8_kernel<<<dim3(nwg), dim3(512), 0, stream>>>(Xq, Wq, bias, amax, out, M, N, K, nbn);
}

// Round 7
// 128.396 us; speedup vs baseline: 1.3608x; 1.0468x over previous
//
#include <hip/hip_runtime.h>
#include <hip/hip_bf16.h>

typedef float f32x4 __attribute__((ext_vector_type(4)));
typedef long lx2 __attribute__((ext_vector_type(2)));

#define FP8_MAX_F 448.0f

__device__ __forceinline__ float wave_max(float m) {
#pragma unroll
    for (int off = 32; off > 0; off >>= 1)
        m = fmaxf(m, __shfl_xor(m, off));
    return m;
}

// ---------------- stage 1: per-block abs-max partials (no atomics) ----------------
__global__ void amax2_kernel(const float* __restrict__ x, long nx,
                             const float* __restrict__ w, long nw,
                             float* __restrict__ px, float* __restrict__ pw,
                             int ga) {
    __shared__ float red[4];
    const float* src; long n; float* dst; int bid, blocks;
    if ((int)blockIdx.x < ga) { src = x; n = nx; dst = px; bid = blockIdx.x; blocks = ga; }
    else { src = w; n = nw; dst = pw; bid = blockIdx.x - ga; blocks = gridDim.x - ga; }

    const long stride = (long)blocks * blockDim.x * 16;
    long i = ((long)bid * blockDim.x + threadIdx.x) * 16;
    float m = 0.0f;
    for (; i < n; i += stride) {
        f32x4 v0 = *(const f32x4*)(src + i);
        f32x4 v1 = *(const f32x4*)(src + i + 4);
        f32x4 v2 = *(const f32x4*)(src + i + 8);
        f32x4 v3 = *(const f32x4*)(src + i + 12);
        float m0 = fmaxf(fmaxf(fabsf(v0.x), fabsf(v0.y)), fmaxf(fabsf(v0.z), fabsf(v0.w)));
        float m1 = fmaxf(fmaxf(fabsf(v1.x), fabsf(v1.y)), fmaxf(fabsf(v1.z), fabsf(v1.w)));
        float m2 = fmaxf(fmaxf(fabsf(v2.x), fabsf(v2.y)), fmaxf(fabsf(v2.z), fabsf(v2.w)));
        float m3 = fmaxf(fmaxf(fabsf(v3.x), fabsf(v3.y)), fmaxf(fabsf(v3.z), fabsf(v3.w)));
        m = fmaxf(m, fmaxf(fmaxf(m0, m1), fmaxf(m2, m3)));
    }
    m = wave_max(m);
    const int wave = threadIdx.x >> 6;
    if ((threadIdx.x & 63) == 0) red[wave] = m;
    __syncthreads();
    if (threadIdx.x == 0)
        dst[bid] = fmaxf(fmaxf(red[0], red[1]), fmaxf(red[2], red[3]));
}

// ---------------- stage 2: reduce partials -> amax bits (block 0 = x, block 1 = w) ----------------
__global__ void amax_final_kernel(const float* __restrict__ px, int npx,
                                  const float* __restrict__ pw, int npw,
                                  unsigned* __restrict__ amax) {
    __shared__ float red[4];
    const float* p; int n;
    if (blockIdx.x == 0) { p = px; n = npx; } else { p = pw; n = npw; }
    float m = 0.0f;
    for (int i = threadIdx.x; i < n; i += blockDim.x) m = fmaxf(m, p[i]);
    m = wave_max(m);
    const int wave = threadIdx.x >> 6;
    if ((threadIdx.x & 63) == 0) red[wave] = m;
    __syncthreads();
    if (threadIdx.x == 0) {
        m = fmaxf(fmaxf(red[0], red[1]), fmaxf(red[2], red[3]));
        amax[blockIdx.x] = __float_as_uint(m);
    }
}

// ---------------- fused quantize (8 floats/thread/iter -> uint2) ----------------
__global__ void quant2_kernel(const float* __restrict__ x, long nx8,
                              const float* __restrict__ w, long nw8,
                              const unsigned* __restrict__ amax_bits,
                              unsigned* __restrict__ qx, unsigned* __restrict__ qw,
                              int ga) {
    const float* src; long n8; unsigned* q; int bid, blocks; float a;
    if ((int)blockIdx.x < ga) { src = x; n8 = nx8; q = qx; bid = blockIdx.x; blocks = ga;
                                a = __uint_as_float(amax_bits[0]); }
    else { src = w; n8 = nw8; q = qw; bid = blockIdx.x - ga; blocks = gridDim.x - ga;
           a = __uint_as_float(amax_bits[1]); }
    const float scale = fminf(FP8_MAX_F / fmaxf(a, 1e-12f), FP8_MAX_F);

    const long stride = (long)blocks * blockDim.x;
    for (long i = (long)bid * blockDim.x + threadIdx.x; i < n8; i += stride) {
        f32x4 v0 = *(const f32x4*)(src + i * 8);
        f32x4 v1 = *(const f32x4*)(src + i * 8 + 4);
        float c0 = fminf(fmaxf(v0.x * scale, -FP8_MAX_F), FP8_MAX_F);
        float c1 = fminf(fmaxf(v0.y * scale, -FP8_MAX_F), FP8_MAX_F);
        float c2 = fminf(fmaxf(v0.z * scale, -FP8_MAX_F), FP8_MAX_F);
        float c3 = fminf(fmaxf(v0.w * scale, -FP8_MAX_F), FP8_MAX_F);
        float c4 = fminf(fmaxf(v1.x * scale, -FP8_MAX_F), FP8_MAX_F);
        float c5 = fminf(fmaxf(v1.y * scale, -FP8_MAX_F), FP8_MAX_F);
        float c6 = fminf(fmaxf(v1.z * scale, -FP8_MAX_F), FP8_MAX_F);
        float c7 = fminf(fmaxf(v1.w * scale, -FP8_MAX_F), FP8_MAX_F);
        int r0 = __builtin_amdgcn_cvt_pk_fp8_f32(c0, c1, 0, false);
        r0 = __builtin_amdgcn_cvt_pk_fp8_f32(c2, c3, r0, true);
        int r1 = __builtin_amdgcn_cvt_pk_fp8_f32(c4, c5, 0, false);
        r1 = __builtin_amdgcn_cvt_pk_fp8_f32(c6, c7, r1, true);
        uint2 rr; rr.x = (unsigned)r0; rr.y = (unsigned)r1;
        *(uint2*)(q + i * 2) = rr;
    }
}

// ---------------- fp8 GEMM, 256x256 tile, BK=64, counted-interleave, 1 barrier/tile ----------------
// LDS per slot/side: linear [c=0..3][row=0..255][16B]; lane (l15,lhi) ds_read_b128's unit
// (row, c=lhi); bytes 0..7 = MFMA k-step 0, 8..15 = k-step 1 (same map A and B) ->
// bank-conflict-free (verified R4/R6: SQ_LDS_BANK_CONFLICT = 0).
// Pipeline (3 slots): during tile t, issue stage(t+2); reads for t+1 happen post-BAR(t)
// under MFMA#2. Counted waits: lgkmcnt(4) = last tile's af/bf (DS retires in order),
// lgkmcnt(0) pre-BAR = ag drained (WAR safety), vmcnt(4) = S(t+1) landed, S(t+2) in flight.
// All readers of a slot drain BEFORE the barrier that precedes its restage.
__global__ __launch_bounds__(512, 2) void gemm_fp8_kernel(
    const unsigned char* __restrict__ Xq,   // [M][K] fp8
    const unsigned char* __restrict__ Wq,   // [N][K] fp8
    const float* __restrict__ bias,         // [N]
    const unsigned* __restrict__ amax_bits, // [0]=x amax, [1]=w amax
    float* __restrict__ out,                // [M][N] f32 (bf16-rounded values)
    int M, int N, int K, int nbn)
{
    __shared__ unsigned char ldsA[3][16384];
    __shared__ unsigned char ldsB[3][16384];

    const int tid  = threadIdx.x;
    const int lane = tid & 63;
    const int wave = tid >> 6;
    const int wm128 = (wave >> 2) * 128;  // 2 M-halves
    const int wn64  = (wave & 3) * 64;    // 4 N-quarters

    const int l15 = lane & 15;
    const int lhi = lane >> 4;            // 0..3 -> which 16B k-chunk

    // XCD-aware swizzle (nwg % 8 == 0), bn-fastest for A-panel L2 reuse
    const int cpx = gridDim.x >> 3;
    const int wg  = ((int)blockIdx.x & 7) * cpx + ((int)blockIdx.x >> 3);
    const int bn = wg % nbn;
    const int bm = wg / nbn;
    const int rowStart = bm << 8;
    const int colStart = bn << 8;

    // LDS read offsets (linear layout)
    const int aoff0 = lhi * 4096 + (wm128 + l15) * 16;   // mh=0; mh=1 at +1024
    const int boff  = lhi * 4096 + (wn64 + l15) * 16;

    // staging source offsets (fully linear)
    const size_t aoffs = (size_t)(rowStart + (tid & 255)) * K + (tid >> 8) * 16;
    const size_t boffs = (size_t)(colStart + (tid & 255)) * K + (tid >> 8) * 16;
    const int tid16 = tid * 16;

    f32x4 acc[8][4] = {};

#define STAGE_A(t, sl)                                                                          \
    do {                                                                                        \
        const size_t kk_ = (size_t)(t) * 64;                                                    \
        __builtin_amdgcn_global_load_lds(                                                       \
            (const __attribute__((address_space(1))) void*)(Xq + aoffs + kk_),                  \
            (__attribute__((address_space(3))) void*)(&ldsA[sl][tid16]), 16, 0, 0);             \
        __builtin_amdgcn_global_load_lds(                                                       \
            (const __attribute__((address_space(1))) void*)(Xq + aoffs + 32 + kk_),             \
            (__attribute__((address_space(3))) void*)(&ldsA[sl][8192 + tid16]), 16, 0, 0);      \
    } while (0)

#define STAGE_B(t, sl)                                                                          \
    do {                                                                                        \
        const size_t kk_ = (size_t)(t) * 64;                                                    \
        __builtin_amdgcn_global_load_lds(                                                       \
            (const __attribute__((address_space(1))) void*)(Wq + boffs + kk_),                  \
            (__attribute__((address_space(3))) void*)(&ldsB[sl][tid16]), 16, 0, 0);             \
        __builtin_amdgcn_global_load_lds(                                                       \
            (const __attribute__((address_space(1))) void*)(Wq + boffs + 32 + kk_),             \
            (__attribute__((address_space(3))) void*)(&ldsB[sl][8192 + tid16]), 16, 0, 0);      \
    } while (0)

#define MFMA32(AF, BF, MO)                                                                      \
    do {                                                                                        \
        __builtin_amdgcn_s_setprio(1);                                                          \
        _Pragma("unroll")                                                                       \
        for (int ks_ = 0; ks_ < 2; ++ks_)                                                       \
            _Pragma("unroll")                                                                   \
            for (int mi_ = 0; mi_ < 4; ++mi_)                                                   \
                _Pragma("unroll")                                                               \
                for (int ni_ = 0; ni_ < 4; ++ni_)                                               \
                    acc[(MO) + mi_][ni_] = __builtin_amdgcn_mfma_f32_16x16x32_fp8_fp8(          \
                        AF[mi_][ks_], BF[ni_][ks_], acc[(MO) + mi_][ni_], 0, 0, 0);             \
        __builtin_amdgcn_s_setprio(0);                                                          \
    } while (0)

// One K-tile. AF/BF: fragments for THIS tile (read during previous tile, post-BAR).
// AF2/BF2: fragments for the NEXT tile, read here post-BAR under MFMA#2.
#define BODY(t, sA, AF, BF, AF2, BF2)                                                           \
    do {                                                                                        \
        const int s_  = (sA);                                                                   \
        const int s1_ = (s_ + 1 >= 3) ? s_ - 2 : s_ + 1;                                        \
        const int s2_ = (s_ + 2 >= 3) ? s_ - 1 : s_ + 2;                                        \
        const unsigned char* bA_ = &ldsA[s_][0];                                                \
        _Pragma("unroll")                                                                       \
        for (int q_ = 0; q_ < 4; ++q_)                                                          \
            ag[q_] = *(const lx2*)(bA_ + aoff0 + 1024 + q_ * 256);                              \
        if ((t) + 2 < nT) { STAGE_A((t) + 2, s2_); STAGE_B((t) + 2, s2_); }                     \
        asm volatile("s_waitcnt lgkmcnt(4)" ::: "memory");  /* AF,BF ready; ag in flight */     \
        __builtin_amdgcn_sched_barrier(0);                                                      \
        MFMA32(AF, BF, 0);                                                                      \
        asm volatile("s_waitcnt lgkmcnt(0)" ::: "memory");  /* ag drained (WAR, pre-BAR) */     \
        if ((t) + 2 < nT) asm volatile("s_waitcnt vmcnt(4)" ::: "memory");                      \
        else              asm volatile("s_waitcnt vmcnt(0)" ::: "memory");                      \
        __builtin_amdgcn_s_barrier();                                                           \
        __builtin_amdgcn_sched_barrier(0);                                                      \
        if ((t) + 1 < nT) {                                                                     \
            const unsigned char* nA_ = &ldsA[s1_][0];                                           \
            const unsigned char* nB_ = &ldsB[s1_][0];                                           \
            _Pragma("unroll")                                                                   \
            for (int q_ = 0; q_ < 4; ++q_) {                                                    \
                AF2[q_] = *(const lx2*)(nA_ + aoff0 + q_ * 256);                                \
                BF2[q_] = *(const lx2*)(nB_ + boff + q_ * 256);                                 \
            }                                                                                   \
        }                                                                                       \
        MFMA32(ag, BF, 4);                                                                      \
    } while (0)

    // prologue: stage tiles 0,1 -> slots 0,1; publish tile 0; preload its fragments
    STAGE_A(0, 0); STAGE_B(0, 0);
    STAGE_A(1, 1); STAGE_B(1, 1);
    asm volatile("s_waitcnt vmcnt(4)" ::: "memory");   // S(0) landed, S(1) in flight
    __builtin_amdgcn_s_barrier();
    __builtin_amdgcn_sched_barrier(0);

    lx2 afA[4], bfA[4], afB[4], bfB[4], ag[4];
#pragma unroll
    for (int q_ = 0; q_ < 4; ++q_) {
        afA[q_] = *(const lx2*)(&ldsA[0][aoff0 + q_ * 256]);
        bfA[q_] = *(const lx2*)(&ldsB[0][boff + q_ * 256]);
    }

    const int nT = K >> 6;   // 16
    int s = 0;
#pragma unroll 1
    for (int t = 0; t < nT; t += 2) {
        const int sn = (s + 1 >= 3) ? s - 2 : s + 1;
        BODY(t,     s,  afA, bfA, afB, bfB);
        BODY(t + 1, sn, afB, bfB, afA, bfA);
        s = (s + 2 >= 3) ? s - 1 : s + 2;
    }
#undef BODY
#undef MFMA32
#undef STAGE_A
#undef STAGE_B

    // ---- epilogue: dequant scale, bias, bf16 round, f32 store ----
    const float ax = __uint_as_float(amax_bits[0]);
    const float aw = __uint_as_float(amax_bits[1]);
    const float sx = fminf(FP8_MAX_F / fmaxf(ax, 1e-12f), FP8_MAX_F);
    const float sw = fminf(FP8_MAX_F / fmaxf(aw, 1e-12f), FP8_MAX_F);
    const float sc = (1.0f / sx) * (1.0f / sw);

    const int lhi4 = lhi * 4;
#pragma unroll
    for (int ni = 0; ni < 4; ++ni) {
        const int col = colStart + wn64 + ni * 16 + l15;
        const float bv = bias[col];
#pragma unroll
        for (int mi = 0; mi < 8; ++mi) {
            const size_t rbase = (size_t)(rowStart + wm128 + mi * 16 + lhi4) * N + col;
#pragma unroll
            for (int j = 0; j < 4; ++j) {
                float t = acc[mi][ni][j] * sc;  // mul...
                t = t + bv;                     // ...then add (match jnp op order)
                out[rbase + (size_t)j * N] = __bfloat162float(__float2bfloat16(t));
            }
        }
    }
}

extern "C" void kernel_launch(void* const* d_in, const int* in_sizes, int n_in,
                              void* d_out, int out_size, void* d_ws, size_t ws_size,
                              hipStream_t stream) {
    const float* input  = (const float*)d_in[0];
    const float* weight = (const float*)d_in[1];
    const float* bias   = (const float*)d_in[2];
    float* out = (float*)d_out;

    const int K = 1024;                       // weight [N,K] = [1024,1024]
    const int N = in_sizes[2];                // 1024 (bias length)
    const long nX = in_sizes[0];              // 33554432
    const long nW = (long)N * K;              // 1048576
    const int M = (int)(nX / K);              // 32768

    const int GA = 1984;                      // input blocks (of 2048 total)
    const int GW = 64;                        // weight blocks

    unsigned char* ws = (unsigned char*)d_ws;
    unsigned* amax = (unsigned*)ws;           // [0]=x amax bits, [1]=w amax bits
    unsigned char* Xq = ws + 256;
    unsigned char* Wq = Xq + (size_t)M * K;
    float* px = (float*)(Wq + (size_t)N * K); // 1984 partials
    float* pw = px + GA;                      // 64 partials

    // stage 1: per-block partials (plain stores, no atomic contention)
    amax2_kernel<<<GA + GW, 256, 0, stream>>>(input, nX, weight, nW, px, pw, GA);
    // stage 2: 2 blocks reduce partials -> amax bits (deterministic)
    amax_final_kernel<<<2, 256, 0, stream>>>(px, GA, pw, GW, amax);

    quant2_kernel<<<2048, 256, 0, stream>>>(input, nX / 8, weight, nW / 8, amax,
                                            (unsigned*)Xq, (unsigned*)Wq, GA);

    const int nbn = N / 256;                  // 4
    const int nwg = (M / 256) * nbn;          // 512
    gemm_fp8_kernel<<<dim3(nwg), dim3(512), 0, stream>>>(Xq, Wq, bias, amax, out, M, N, K, nbn);
}

// Round 8
// 119.495 us; speedup vs baseline: 1.4622x; 1.0745x over previous
//
#include <hip/hip_runtime.h>
#include <hip/hip_bf16.h>

typedef float f32x4 __attribute__((ext_vector_type(4)));
typedef float f32x16 __attribute__((ext_vector_type(16)));
typedef int   i32x4  __attribute__((ext_vector_type(4)));
typedef int   i32x8  __attribute__((ext_vector_type(8)));

#define FP8_MAX_F 448.0f
#define SCL1 0x7F7F7F7Fu   /* e8m0 exponent 127 -> scale 1.0, all 4 bytes */

__device__ __forceinline__ float wave_max(float m) {
#pragma unroll
    for (int off = 32; off > 0; off >>= 1)
        m = fmaxf(m, __shfl_xor(m, off));
    return m;
}

// ---------------- stage 1: per-block abs-max partials (no atomics) ----------------
__global__ void amax2_kernel(const float* __restrict__ x, long nx,
                             const float* __restrict__ w, long nw,
                             float* __restrict__ px, float* __restrict__ pw,
                             int ga) {
    __shared__ float red[4];
    const float* src; long n; float* dst; int bid, blocks;
    if ((int)blockIdx.x < ga) { src = x; n = nx; dst = px; bid = blockIdx.x; blocks = ga; }
    else { src = w; n = nw; dst = pw; bid = blockIdx.x - ga; blocks = gridDim.x - ga; }

    const long stride = (long)blocks * blockDim.x * 16;
    long i = ((long)bid * blockDim.x + threadIdx.x) * 16;
    float m = 0.0f;
    for (; i < n; i += stride) {
        f32x4 v0 = *(const f32x4*)(src + i);
        f32x4 v1 = *(const f32x4*)(src + i + 4);
        f32x4 v2 = *(const f32x4*)(src + i + 8);
        f32x4 v3 = *(const f32x4*)(src + i + 12);
        float m0 = fmaxf(fmaxf(fabsf(v0.x), fabsf(v0.y)), fmaxf(fabsf(v0.z), fabsf(v0.w)));
        float m1 = fmaxf(fmaxf(fabsf(v1.x), fabsf(v1.y)), fmaxf(fabsf(v1.z), fabsf(v1.w)));
        float m2 = fmaxf(fmaxf(fabsf(v2.x), fabsf(v2.y)), fmaxf(fabsf(v2.z), fabsf(v2.w)));
        float m3 = fmaxf(fmaxf(fabsf(v3.x), fabsf(v3.y)), fmaxf(fabsf(v3.z), fabsf(v3.w)));
        m = fmaxf(m, fmaxf(fmaxf(m0, m1), fmaxf(m2, m3)));
    }
    m = wave_max(m);
    const int wave = threadIdx.x >> 6;
    if ((threadIdx.x & 63) == 0) red[wave] = m;
    __syncthreads();
    if (threadIdx.x == 0)
        dst[bid] = fmaxf(fmaxf(red[0], red[1]), fmaxf(red[2], red[3]));
}

// ---------------- stage 2: reduce partials -> amax bits (block 0 = x, block 1 = w) ----------------
__global__ void amax_final_kernel(const float* __restrict__ px, int npx,
                                  const float* __restrict__ pw, int npw,
                                  unsigned* __restrict__ amax) {
    __shared__ float red[4];
    const float* p; int n;
    if (blockIdx.x == 0) { p = px; n = npx; } else { p = pw; n = npw; }
    float m = 0.0f;
    for (int i = threadIdx.x; i < n; i += blockDim.x) m = fmaxf(m, p[i]);
    m = wave_max(m);
    const int wave = threadIdx.x >> 6;
    if ((threadIdx.x & 63) == 0) red[wave] = m;
    __syncthreads();
    if (threadIdx.x == 0) {
        m = fmaxf(fmaxf(red[0], red[1]), fmaxf(red[2], red[3]));
        amax[blockIdx.x] = __float_as_uint(m);
    }
}

// ---------------- fused quantize (8 floats/thread/iter -> uint2) ----------------
__global__ void quant2_kernel(const float* __restrict__ x, long nx8,
                              const float* __restrict__ w, long nw8,
                              const unsigned* __restrict__ amax_bits,
                              unsigned* __restrict__ qx, unsigned* __restrict__ qw,
                              int ga) {
    const float* src; long n8; unsigned* q; int bid, blocks; float a;
    if ((int)blockIdx.x < ga) { src = x; n8 = nx8; q = qx; bid = blockIdx.x; blocks = ga;
                                a = __uint_as_float(amax_bits[0]); }
    else { src = w; n8 = nw8; q = qw; bid = blockIdx.x - ga; blocks = gridDim.x - ga;
           a = __uint_as_float(amax_bits[1]); }
    const float scale = fminf(FP8_MAX_F / fmaxf(a, 1e-12f), FP8_MAX_F);

    const long stride = (long)blocks * blockDim.x;
    for (long i = (long)bid * blockDim.x + threadIdx.x; i < n8; i += stride) {
        f32x4 v0 = *(const f32x4*)(src + i * 8);
        f32x4 v1 = *(const f32x4*)(src + i * 8 + 4);
        float c0 = fminf(fmaxf(v0.x * scale, -FP8_MAX_F), FP8_MAX_F);
        float c1 = fminf(fmaxf(v0.y * scale, -FP8_MAX_F), FP8_MAX_F);
        float c2 = fminf(fmaxf(v0.z * scale, -FP8_MAX_F), FP8_MAX_F);
        float c3 = fminf(fmaxf(v0.w * scale, -FP8_MAX_F), FP8_MAX_F);
        float c4 = fminf(fmaxf(v1.x * scale, -FP8_MAX_F), FP8_MAX_F);
        float c5 = fminf(fmaxf(v1.y * scale, -FP8_MAX_F), FP8_MAX_F);
        float c6 = fminf(fmaxf(v1.z * scale, -FP8_MAX_F), FP8_MAX_F);
        float c7 = fminf(fmaxf(v1.w * scale, -FP8_MAX_F), FP8_MAX_F);
        int r0 = __builtin_amdgcn_cvt_pk_fp8_f32(c0, c1, 0, false);
        r0 = __builtin_amdgcn_cvt_pk_fp8_f32(c2, c3, r0, true);
        int r1 = __builtin_amdgcn_cvt_pk_fp8_f32(c4, c5, 0, false);
        r1 = __builtin_amdgcn_cvt_pk_fp8_f32(c6, c7, r1, true);
        uint2 rr; rr.x = (unsigned)r0; rr.y = (unsigned)r1;
        *(uint2*)(q + i * 2) = rr;
    }
}

// ---------------- fp8 GEMM, 256x256 tile, BK=64, mfma_scale 32x32x64 (unit scales) ----------------
// LDS per slot/side: linear [c=0..3][row=0..255][16B] (R4/R6/R7-verified conflict-free).
// Lane (l31 = l&31, g = l>>5) reads units (row, c=2g) and (row, c=2g+1) -> 32 K-bytes.
// k -> (group, slot) map identical on A and B => any bijection is correct (MFMA pairs
// A-slot j of group g with B-slot j of group g; A/B fragments are symmetric).
// Unit e8m0 scales (0x7F = 2^0) make mfma_scale numerically == plain fp8 GEMM at 2.3x rate.
// Pipeline: R7's 3-slot, 1-barrier/tile, counted vmcnt(4) skeleton (race-proof carried over).
__global__ __launch_bounds__(512, 1) void gemm_fp8_kernel(
    const unsigned char* __restrict__ Xq,   // [M][K] fp8
    const unsigned char* __restrict__ Wq,   // [N][K] fp8
    const float* __restrict__ bias,         // [N]
    const unsigned* __restrict__ amax_bits, // [0]=x amax, [1]=w amax
    float* __restrict__ out,                // [M][N] f32 (bf16-rounded values)
    int M, int N, int K, int nbn)
{
    __shared__ unsigned char ldsA[3][16384];
    __shared__ unsigned char ldsB[3][16384];

    const int tid  = threadIdx.x;
    const int lane = tid & 63;
    const int wave = tid >> 6;
    const int wm128 = (wave >> 2) * 128;  // 2 M-halves
    const int wn64  = (wave & 3) * 64;    // 4 N-quarters

    const int l31 = lane & 31;
    const int g   = lane >> 5;            // k-group: 0 -> k 0..31, 1 -> k 32..63

    // XCD-aware swizzle (nwg % 8 == 0), bn-fastest for A-panel L2 reuse
    const int cpx = gridDim.x >> 3;
    const int wg  = ((int)blockIdx.x & 7) * cpx + ((int)blockIdx.x >> 3);
    const int bn = wg % nbn;
    const int bm = wg / nbn;
    const int rowStart = bm << 8;
    const int colStart = bn << 8;

    // LDS read offsets: low 16B at c=2g, high 16B at c=2g+1 (+4096)
    const int aoffL = (2 * g) * 4096 + (wm128 + l31) * 16;   // + mt*512
    const int boffL = (2 * g) * 4096 + (wn64  + l31) * 16;   // + nt*512

    // staging source offsets (fully linear; dest = tid*16, wave-uniform base + lane*16)
    const size_t aoffs = (size_t)(rowStart + (tid & 255)) * K + (tid >> 8) * 16;
    const size_t boffs = (size_t)(colStart + (tid & 255)) * K + (tid >> 8) * 16;
    const int tid16 = tid * 16;

    union Frag { i32x8 v; struct { i32x4 lo, hi; } h; };
    f32x16 acc[4][2] = {};

#define STAGE_A(t, sl)                                                                          \
    do {                                                                                        \
        const size_t kk_ = (size_t)(t) * 64;                                                    \
        __builtin_amdgcn_global_load_lds(                                                       \
            (const __attribute__((address_space(1))) void*)(Xq + aoffs + kk_),                  \
            (__attribute__((address_space(3))) void*)(&ldsA[sl][tid16]), 16, 0, 0);             \
        __builtin_amdgcn_global_load_lds(                                                       \
            (const __attribute__((address_space(1))) void*)(Xq + aoffs + 32 + kk_),             \
            (__attribute__((address_space(3))) void*)(&ldsA[sl][8192 + tid16]), 16, 0, 0);      \
    } while (0)

#define STAGE_B(t, sl)                                                                          \
    do {                                                                                        \
        const size_t kk_ = (size_t)(t) * 64;                                                    \
        __builtin_amdgcn_global_load_lds(                                                       \
            (const __attribute__((address_space(1))) void*)(Wq + boffs + kk_),                  \
            (__attribute__((address_space(3))) void*)(&ldsB[sl][tid16]), 16, 0, 0);             \
        __builtin_amdgcn_global_load_lds(                                                       \
            (const __attribute__((address_space(1))) void*)(Wq + boffs + 32 + kk_),             \
            (__attribute__((address_space(3))) void*)(&ldsB[sl][8192 + tid16]), 16, 0, 0);      \
    } while (0)

#define RD_FRAGS(sl, FA, FB)                                                                    \
    do {                                                                                        \
        const unsigned char* rA_ = &ldsA[sl][0];                                                \
        const unsigned char* rB_ = &ldsB[sl][0];                                                \
        _Pragma("unroll")                                                                       \
        for (int mt_ = 0; mt_ < 4; ++mt_) {                                                     \
            FA[mt_].h.lo = *(const i32x4*)(rA_ + aoffL + mt_ * 512);                            \
            FA[mt_].h.hi = *(const i32x4*)(rA_ + aoffL + 4096 + mt_ * 512);                     \
        }                                                                                       \
        _Pragma("unroll")                                                                       \
        for (int nt_ = 0; nt_ < 2; ++nt_) {                                                     \
            FB[nt_].h.lo = *(const i32x4*)(rB_ + boffL + nt_ * 512);                            \
            FB[nt_].h.hi = *(const i32x4*)(rB_ + boffL + 4096 + nt_ * 512);                     \
        }                                                                                       \
    } while (0)

#define MFMA8(FA, FB)                                                                           \
    do {                                                                                        \
        __builtin_amdgcn_s_setprio(1);                                                          \
        _Pragma("unroll")                                                                       \
        for (int mt_ = 0; mt_ < 4; ++mt_)                                                       \
            _Pragma("unroll")                                                                   \
            for (int nt_ = 0; nt_ < 2; ++nt_)                                                   \
                acc[mt_][nt_] = __builtin_amdgcn_mfma_scale_f32_32x32x64_f8f6f4(                \
                    FA[mt_].v, FB[nt_].v, acc[mt_][nt_], 0, 0, 0, SCL1, 0, SCL1);               \
        __builtin_amdgcn_s_setprio(0);                                                          \
    } while (0)

// One K-tile: stage(t+2) -> lgkm0 (this tile's frags ready) -> 8 MFMA ->
// counted vmcnt(4) (S(t+1) landed, S(t+2) in flight) -> barrier -> read frags of t+1.
#define BODY(t, sNext, sStage, FA, FB, FA2, FB2)                                                \
    do {                                                                                        \
        if ((t) + 2 < nT) { STAGE_A((t) + 2, sStage); STAGE_B((t) + 2, sStage); }               \
        asm volatile("s_waitcnt lgkmcnt(0)" ::: "memory");                                      \
        __builtin_amdgcn_sched_barrier(0);                                                      \
        MFMA8(FA, FB);                                                                          \
        if ((t) + 2 < nT) asm volatile("s_waitcnt vmcnt(4)" ::: "memory");                      \
        else              asm volatile("s_waitcnt vmcnt(0)" ::: "memory");                      \
        __builtin_amdgcn_s_barrier();                                                           \
        __builtin_amdgcn_sched_barrier(0);                                                      \
        if ((t) + 1 < nT) RD_FRAGS(sNext, FA2, FB2);                                            \
    } while (0)

    // prologue: stage tiles 0,1 -> slots 0,1; publish tile 0 (S(1) stays in flight)
    STAGE_A(0, 0); STAGE_B(0, 0);
    STAGE_A(1, 1); STAGE_B(1, 1);
    asm volatile("s_waitcnt vmcnt(4)" ::: "memory");
    __builtin_amdgcn_s_barrier();
    __builtin_amdgcn_sched_barrier(0);

    Frag faA[4], fbA[2], faB[4], fbB[2];
    RD_FRAGS(0, faA, fbA);

    const int nT = K >> 6;   // 16
    int s = 0;
#pragma unroll 1
    for (int t = 0; t < nT; t += 2) {
        const int s1 = (s + 1 >= 3) ? s - 2 : s + 1;
        const int s2 = (s + 2 >= 3) ? s - 1 : s + 2;
        BODY(t,     s1, s2, faA, fbA, faB, fbB);   // tile t in slot s
        BODY(t + 1, s2, s,  faB, fbB, faA, fbA);   // tile t+1 in slot s1; stage t+3 -> s
        s = s2;
    }
#undef BODY
#undef MFMA8
#undef RD_FRAGS
#undef STAGE_A
#undef STAGE_B

    // ---- epilogue: dequant scale, bias, bf16 round, f32 store ----
    // 32x32 C/D layout: col = lane&31, row = (r&3) + 8*(r>>2) + 4*(lane>>5)
    const float ax = __uint_as_float(amax_bits[0]);
    const float aw = __uint_as_float(amax_bits[1]);
    const float sx = fminf(FP8_MAX_F / fmaxf(ax, 1e-12f), FP8_MAX_F);
    const float sw = fminf(FP8_MAX_F / fmaxf(aw, 1e-12f), FP8_MAX_F);
    const float sc = (1.0f / sx) * (1.0f / sw);

#pragma unroll
    for (int nt = 0; nt < 2; ++nt) {
        const int col = colStart + wn64 + nt * 32 + l31;
        const float bv = bias[col];
#pragma unroll
        for (int mt = 0; mt < 4; ++mt) {
#pragma unroll
            for (int r = 0; r < 16; ++r) {
                const int row = rowStart + wm128 + mt * 32 + (r & 3) + 8 * (r >> 2) + 4 * g;
                float tt = acc[mt][nt][r] * sc;   // mul...
                tt = tt + bv;                     // ...then add (match jnp op order)
                out[(size_t)row * N + col] = __bfloat162float(__float2bfloat16(tt));
            }
        }
    }
}

extern "C" void kernel_launch(void* const* d_in, const int* in_sizes, int n_in,
                              void* d_out, int out_size, void* d_ws, size_t ws_size,
                              hipStream_t stream) {
    const float* input  = (const float*)d_in[0];
    const float* weight = (const float*)d_in[1];
    const float* bias   = (const float*)d_in[2];
    float* out = (float*)d_out;

    const int K = 1024;                       // weight [N,K] = [1024,1024]
    const int N = in_sizes[2];                // 1024 (bias length)
    const long nX = in_sizes[0];              // 33554432
    const long nW = (long)N * K;              // 1048576
    const int M = (int)(nX / K);              // 32768

    const int GA = 1984;                      // input blocks (of 2048 total)
    const int GW = 64;                        // weight blocks

    unsigned char* ws = (unsigned char*)d_ws;
    unsigned* amax = (unsigned*)ws;           // [0]=x amax bits, [1]=w amax bits
    unsigned char* Xq = ws + 256;
    unsigned char* Wq = Xq + (size_t)M * K;
    float* px = (float*)(Wq + (size_t)N * K); // 1984 partials
    float* pw = px + GA;                      // 64 partials

    // stage 1: per-block partials (plain stores, no atomic contention)
    amax2_kernel<<<GA + GW, 256, 0, stream>>>(input, nX, weight, nW, px, pw, GA);
    // stage 2: 2 blocks reduce partials -> amax bits (deterministic)
    amax_final_kernel<<<2, 256, 0, stream>>>(px, GA, pw, GW, amax);

    quant2_kernel<<<2048, 256, 0, stream>>>(input, nX / 8, weight, nW / 8, amax,
                                            (unsigned*)Xq, (unsigned*)Wq, GA);

    const int nbn = N / 256;                  // 4
    const int nwg = (M / 256) * nbn;          // 512
    gemm_fp8_kernel<<<dim3(nwg), dim3(512), 0, stream>>>(Xq, Wq, bias, amax, out, M, N, K, nbn);
}